// Round 1
// baseline (6526.973 us; speedup 1.0000x reference)
//
#include <hip/hip_runtime.h>
#include <math.h>

#define B_  2
#define S_  2048
#define D_  1024
#define H_  16
#define DP_ 64
#define TQ  8

// ---------------------------------------------------------------------------
// fp32 tiled GEMM: C[m,n] = sum_k A[m,k] * W[k,n] + bias[n]
// M=4096 (b*S+s), N=1024, K=1024.
// MODE 0: A plain row-major [M,K]; output permuted to per-head [B,H,S,64].
// MODE 1: A gathered from per-head ctx layout [B,H,S,64]; output plain [M,N].
// Tile 128x128, BK=8, 256 threads, 8x8 micro-tile per thread.
// ---------------------------------------------------------------------------
template <int MODE>
__device__ __forceinline__ void gemm_body(const float* __restrict__ A,
                                          const float* __restrict__ W,
                                          const float* __restrict__ bias,
                                          float* __restrict__ O) {
    __shared__ float As[8][128];
    __shared__ float Bs[8][128];
    const int tid = threadIdx.x;           // 0..255
    const int tx = tid & 15;               // 0..15
    const int ty = tid >> 4;               // 0..15
    const int rowBase = blockIdx.y * 128;
    const int colBase = blockIdx.x * 128;
    const int aRow = tid >> 1;             // 0..127
    const int aCol = (tid & 1) << 2;       // 0 or 4
    const int bRow = tid >> 5;             // 0..7
    const int bCol = (tid & 31) << 2;      // 0..124

    float acc[8][8];
#pragma unroll
    for (int i = 0; i < 8; ++i)
#pragma unroll
        for (int j = 0; j < 8; ++j) acc[i][j] = 0.f;

    for (int k0 = 0; k0 < D_; k0 += 8) {
        float4 av, bv;
        if (MODE == 0) {
            av = *reinterpret_cast<const float4*>(
                A + (size_t)(rowBase + aRow) * D_ + k0 + aCol);
        } else {
            const int m = rowBase + aRow;
            const int b = m >> 11, s = m & (S_ - 1);
            const int kk = k0 + aCol;
            av = *reinterpret_cast<const float4*>(
                A + (((size_t)(b * H_ + (kk >> 6)) * S_ + s) << 6) + (kk & 63));
        }
        bv = *reinterpret_cast<const float4*>(
            W + (size_t)(k0 + bRow) * D_ + colBase + bCol);

        __syncthreads();  // previous iteration's LDS reads done
        As[aCol + 0][aRow] = av.x;
        As[aCol + 1][aRow] = av.y;
        As[aCol + 2][aRow] = av.z;
        As[aCol + 3][aRow] = av.w;
        *reinterpret_cast<float4*>(&Bs[bRow][bCol]) = bv;
        __syncthreads();

#pragma unroll
        for (int kk = 0; kk < 8; ++kk) {
            float am[8], bn[8];
#pragma unroll
            for (int i = 0; i < 8; ++i) am[i] = As[kk][(ty << 3) + i];
#pragma unroll
            for (int j = 0; j < 8; ++j) bn[j] = Bs[kk][(tx << 3) + j];
#pragma unroll
            for (int i = 0; i < 8; ++i)
#pragma unroll
                for (int j = 0; j < 8; ++j)
                    acc[i][j] = fmaf(am[i], bn[j], acc[i][j]);
        }
    }

#pragma unroll
    for (int i = 0; i < 8; ++i) {
        const int m = rowBase + (ty << 3) + i;
        const int b = m >> 11, s = m & (S_ - 1);
#pragma unroll
        for (int j = 0; j < 8; ++j) {
            const int n = colBase + (tx << 3) + j;
            const float val = acc[i][j] + bias[n];
            if (MODE == 0) {
                // [B,H,S,64] layout for attention
                O[(((size_t)(b * H_ + (n >> 6)) * S_ + s) << 6) + (n & 63)] = val;
            } else {
                O[(size_t)m * D_ + n] = val;
            }
        }
    }
}

__global__ __launch_bounds__(256) void qkv_gemm(
    const float* __restrict__ q_in, const float* __restrict__ k_in,
    const float* __restrict__ v_in, const float* __restrict__ Wq,
    const float* __restrict__ Wk, const float* __restrict__ Wv,
    const float* __restrict__ bq, const float* __restrict__ bk,
    const float* __restrict__ bv, float* __restrict__ Oq,
    float* __restrict__ Ok, float* __restrict__ Ov) {
    const int z = blockIdx.z;
    const float* A = (z == 0) ? q_in : (z == 1) ? k_in : v_in;
    const float* W = (z == 0) ? Wq : (z == 1) ? Wk : Wv;
    const float* bias = (z == 0) ? bq : (z == 1) ? bk : bv;
    float* O = (z == 0) ? Oq : (z == 1) ? Ok : Ov;
    gemm_body<0>(A, W, bias, O);
}

__global__ __launch_bounds__(256) void out_gemm(const float* __restrict__ ctx,
                                                const float* __restrict__ Wo,
                                                const float* __restrict__ bo,
                                                float* __restrict__ O) {
    gemm_body<1>(ctx, Wo, bo, O);
}

// ---------------------------------------------------------------------------
// Fused attention: per block = one (b,h) and TQ=8 query rows.
// Dynamic LDS holds the full 8x2048 fp32 score tile (64 KB) + 16 floats.
// 256 threads = 8 row-groups of 32 lanes.
// ---------------------------------------------------------------------------
__global__ __launch_bounds__(256) void attn_kernel(
    const float* __restrict__ Q, const float* __restrict__ K,
    const float* __restrict__ V, float* __restrict__ attn,
    float* __restrict__ ctx) {
    extern __shared__ float sc[];          // TQ*S_ scores + TQ inv at tail
    float* sinv = sc + TQ * S_;

    const int bh = blockIdx.y;             // 0..31
    const int q0 = blockIdx.x * TQ;        // query tile base
    const int t = threadIdx.x;
    const int r = t >> 5;                  // row within tile, 0..7
    const int lane = t & 31;

    // q row in registers (64 floats)
    const float* __restrict__ qrow = Q + ((size_t)bh * S_ + q0 + r) * DP_;
    float4 qreg[16];
#pragma unroll
    for (int i = 0; i < 16; ++i)
        qreg[i] = reinterpret_cast<const float4*>(qrow)[i];

    const float* __restrict__ Kb = K + (size_t)bh * S_ * DP_;
    const float* __restrict__ Vb = V + (size_t)bh * S_ * DP_;
    float* __restrict__ scr = sc + r * S_;

    // ---- scores: s[r][c] = (q[r] . k[c]) / 8, track running max ----
    float lmax = -1e30f;
    for (int i = 0; i < 64; ++i) {
        const int c = lane + (i << 5);
        const float4* kr = reinterpret_cast<const float4*>(Kb + (size_t)c * DP_);
        float s0 = 0.f, s1 = 0.f, s2 = 0.f, s3 = 0.f;
#pragma unroll
        for (int j = 0; j < 16; j += 4) {
            const float4 k0v = kr[j + 0];
            const float4 k1v = kr[j + 1];
            const float4 k2v = kr[j + 2];
            const float4 k3v = kr[j + 3];
            s0 = fmaf(qreg[j + 0].x, k0v.x, s0);
            s0 = fmaf(qreg[j + 0].y, k0v.y, s0);
            s0 = fmaf(qreg[j + 0].z, k0v.z, s0);
            s0 = fmaf(qreg[j + 0].w, k0v.w, s0);
            s1 = fmaf(qreg[j + 1].x, k1v.x, s1);
            s1 = fmaf(qreg[j + 1].y, k1v.y, s1);
            s1 = fmaf(qreg[j + 1].z, k1v.z, s1);
            s1 = fmaf(qreg[j + 1].w, k1v.w, s1);
            s2 = fmaf(qreg[j + 2].x, k2v.x, s2);
            s2 = fmaf(qreg[j + 2].y, k2v.y, s2);
            s2 = fmaf(qreg[j + 2].z, k2v.z, s2);
            s2 = fmaf(qreg[j + 2].w, k2v.w, s2);
            s3 = fmaf(qreg[j + 3].x, k3v.x, s3);
            s3 = fmaf(qreg[j + 3].y, k3v.y, s3);
            s3 = fmaf(qreg[j + 3].z, k3v.z, s3);
            s3 = fmaf(qreg[j + 3].w, k3v.w, s3);
        }
        const float s = (s0 + s1 + s2 + s3) * 0.125f;
        scr[c] = s;
        lmax = fmaxf(lmax, s);
    }

    // row max across the 32-lane group (xor masks <32 stay in each half-wave)
#pragma unroll
    for (int m = 16; m > 0; m >>= 1) lmax = fmaxf(lmax, __shfl_xor(lmax, m));

    // ---- exp + row sum (scores left UNnormalized in LDS) ----
    float lsum = 0.f;
    for (int i = 0; i < 64; ++i) {
        const int c = lane + (i << 5);
        const float e = __expf(scr[c] - lmax);
        scr[c] = e;
        lsum += e;
    }
#pragma unroll
    for (int m = 16; m > 0; m >>= 1) lsum += __shfl_xor(lsum, m);
    const float inv = 1.0f / lsum;
    if (lane == 0) sinv[r] = inv;
    __syncthreads();  // all scores + sinv visible to all threads

    // ---- coalesced attn write (tile is contiguous: rows q0..q0+7) ----
    {
        const size_t abase = ((size_t)bh * S_ + q0) * S_;
        float4* attn4 = reinterpret_cast<float4*>(attn + abase);
        const float4* sc4 = reinterpret_cast<const float4*>(sc);
        for (int idx = t; idx < TQ * S_ / 4; idx += 256) {
            float4 p = sc4[idx];
            const float iv = sinv[idx >> 9];  // 512 float4 per row
            p.x *= iv; p.y *= iv; p.z *= iv; p.w *= iv;
            attn4[idx] = p;
        }
    }

    // ---- ctx[r][d] = (1/l) * sum_c e[r][c] * v[c][d]; 2 dims per thread ----
    {
        const int d0 = lane << 1;
        const float* vp = Vb + d0;
        float c0 = 0.f, c1 = 0.f, c2 = 0.f, c3 = 0.f;
#pragma unroll 4
        for (int c = 0; c < S_; c += 2) {
            const float p0 = scr[c];
            const float p1 = scr[c + 1];
            const float2 v0 = *reinterpret_cast<const float2*>(vp + (size_t)c * DP_);
            const float2 v1 = *reinterpret_cast<const float2*>(vp + (size_t)(c + 1) * DP_);
            c0 = fmaf(p0, v0.x, c0);
            c1 = fmaf(p0, v0.y, c1);
            c2 = fmaf(p1, v1.x, c2);
            c3 = fmaf(p1, v1.y, c3);
        }
        float2 o;
        o.x = (c0 + c2) * inv;
        o.y = (c1 + c3) * inv;
        *reinterpret_cast<float2*>(ctx + ((size_t)bh * S_ + q0 + r) * DP_ + d0) = o;
    }
}

// ---------------------------------------------------------------------------
extern "C" void kernel_launch(void* const* d_in, const int* in_sizes, int n_in,
                              void* d_out, int out_size, void* d_ws,
                              size_t ws_size, hipStream_t stream) {
    const float* q_in = (const float*)d_in[0];
    const float* k_in = (const float*)d_in[1];
    const float* v_in = (const float*)d_in[2];
    const float* Wq = (const float*)d_in[3];
    const float* bq = (const float*)d_in[4];
    const float* Wk = (const float*)d_in[5];
    const float* bk = (const float*)d_in[6];
    const float* Wv = (const float*)d_in[7];
    const float* bv = (const float*)d_in[8];
    const float* Wo = (const float*)d_in[9];
    const float* bo = (const float*)d_in[10];

    float* out = (float*)d_out;                         // [B,S,D] fp32
    float* attn = out + (size_t)B_ * S_ * D_;           // [B,H,S,S] fp32

    float* ws = (float*)d_ws;
    const size_t qkvN = (size_t)B_ * H_ * S_ * DP_;     // 4,194,304 floats each
    float* Qw = ws;
    float* Kw = ws + qkvN;
    float* Vw = ws + 2 * qkvN;
    float* Cw = ws + 3 * qkvN;

    const dim3 blk(256);

    // 1) Q/K/V projections -> per-head layout
    qkv_gemm<<<dim3(D_ / 128, (B_ * S_) / 128, 3), blk, 0, stream>>>(
        q_in, k_in, v_in, Wq, Wk, Wv, bq, bk, bv, Qw, Kw, Vw);

    // 2) fused scores/softmax/PV; 64KB+64B dynamic LDS needs the attribute
    const int smem = (TQ * S_ + 16) * (int)sizeof(float);
    hipFuncSetAttribute(reinterpret_cast<const void*>(attn_kernel),
                        hipFuncAttributeMaxDynamicSharedMemorySize, smem);
    attn_kernel<<<dim3(S_ / TQ, B_ * H_), blk, smem, stream>>>(Qw, Kw, Vw, attn,
                                                               Cw);

    // 3) output projection
    out_gemm<<<dim3(D_ / 128, (B_ * S_) / 128, 1), blk, 0, stream>>>(Cw, Wo, bo,
                                                                     out);
}